// Round 4
// baseline (436.692 us; speedup 1.0000x reference)
//
#include <hip/hip_runtime.h>
#include <hip/hip_bf16.h>

using int32x4  = __attribute__((ext_vector_type(4))) int;
using int32x16 = __attribute__((ext_vector_type(16))) int;

#define BM 128
#define BN 128
#define BKQ 128  // K-bytes per staging step = 4 x mfma_i32_32x32x32_i8 slices

// ---------------------------------------------------------------------------
// async 16B global->LDS (wave-uniform LDS base + lane*16)
__device__ __forceinline__ void load_lds16(const void* g, void* l) {
    __builtin_amdgcn_global_load_lds(
        (const __attribute__((address_space(1))) unsigned int*)g,
        (__attribute__((address_space(3))) unsigned int*)l, 16, 0, 0);
}

// ---------------------------------------------------------------------------
// Fused prep: blocks [0,M) quantize activations to signed int8 (xq - a_zp)
// + per-row sums; blocks [M, M+WB) convert weights int32 -> int8 (w - 128).
__global__ __launch_bounds__(256) void prep(
    const float* __restrict__ x, const float* __restrict__ act_scale,
    const int* __restrict__ act_zp, char* __restrict__ xs,
    int* __restrict__ rowsum, int K, int M,
    const int4* __restrict__ wq, char4* __restrict__ wsq, long n4)
{
    if (blockIdx.x < (unsigned)M) {
        __shared__ int wsum[4];
        const int row = blockIdx.x;
        const float s = act_scale[0];
        const int zp = act_zp[0];
        const float4* __restrict__ xr = (const float4*)(x + (size_t)row * K);
        char4* __restrict__ xo = (char4*)(xs + (size_t)row * K);
        const int nv = K >> 2;
        int sum = 0;
        for (int i = threadIdx.x; i < nv; i += 256) {
            float4 v = xr[i];
            int q0 = min(max((int)rintf(v.x / s) + zp, 0), 255) - zp;
            int q1 = min(max((int)rintf(v.y / s) + zp, 0), 255) - zp;
            int q2 = min(max((int)rintf(v.z / s) + zp, 0), 255) - zp;
            int q3 = min(max((int)rintf(v.w / s) + zp, 0), 255) - zp;
            sum += q0 + q1 + q2 + q3;
            char4 c;
            c.x = (char)q0; c.y = (char)q1; c.z = (char)q2; c.w = (char)q3;
            xo[i] = c;
        }
        for (int off = 32; off > 0; off >>= 1) sum += __shfl_down(sum, off, 64);
        if ((threadIdx.x & 63) == 0) wsum[threadIdx.x >> 6] = sum;
        __syncthreads();
        if (threadIdx.x == 0) rowsum[row] = wsum[0] + wsum[1] + wsum[2] + wsum[3];
    } else {
        long i = (long)(blockIdx.x - M) * 256 + threadIdx.x;
        if (i >= n4) return;
        int4 v = wq[i];
        char4 c;
        c.x = (char)(v.x - 128); c.y = (char)(v.y - 128);
        c.z = (char)(v.z - 128); c.w = (char)(v.w - 128);
        wsq[i] = c;
    }
}

// ---------------------------------------------------------------------------
// int8 GEMM: round-0 proven structure (128x128 tile, 4 waves, 32 KiB LDS,
// 2-barrier K-loop, ~3 blocks/CU for cross-block latency hiding), with the
// MFMA shape switched 16x16x64 -> 32x32x32 (half the MFMA instructions,
// 4404 vs 3944 TOPS ceiling). Each wave: 64x64 output = 2x2 grid of 32x32.
//
// LDS swizzle (unchanged): physical 16B chunk (row, p) holds logical k-chunk
// c = p ^ (row & 7); staging applies the swizzle to the per-lane GLOBAL
// source; readers XOR with (row & 7).
// 32x32x32 fragment: lane l -> A row = l&31, k-bytes = (l>>5)*16 + [0..15];
// per slice ss (K=32): logical chunk c = ss*2 + (l>>5), phys p = c ^ (l&7).
// C/D: col = lane&31, row = (reg&3) + 8*(reg>>2) + 4*(lane>>5)  [m101].
__global__ __launch_bounds__(256, 4) void gemm_i8(
    const char* __restrict__ Aq, const char* __restrict__ Bq,
    const int* __restrict__ rowsum, const float* __restrict__ wscale,
    const int* __restrict__ wzp, const float* __restrict__ ascale,
    const float* __restrict__ bias, float* __restrict__ C,
    int M, int N, int K)
{
    __shared__ __align__(16) char As[BM * BKQ];  // 16 KiB
    __shared__ __align__(16) char Bs[BN * BKQ];  // 16 KiB

    const int tid  = threadIdx.x;
    const int wave = tid >> 6;
    const int lane = tid & 63;

    const int n0 = blockIdx.x * BN;
    const int m0 = blockIdx.y * BM;

    const int wm = (wave & 1) * 64;   // wave's m-offset in tile
    const int wn = (wave >> 1) * 64;  // wave's n-offset in tile

    // --- staging source addresses (swizzled) --- (verbatim round-0)
    const int srow = wave * 8 + (lane >> 3);            // row within 32-row band
    const int scol = ((lane & 7) ^ (lane >> 3)) * 16;   // swizzled k-chunk byte
    const char* ag = Aq + (size_t)(m0 + srow) * K + scol;
    const char* bg = Bq + (size_t)(n0 + srow) * K + scol;
    const size_t band = (size_t)32 * K;                 // 32-row band stride

    char* lA = As + wave * 1024;
    char* lB = Bs + wave * 1024;

    int32x16 acc[2][2] = {};

    // --- fragment read offsets (32x32x32 pattern) ---
    const int rA = lane & 31;      // row within 32-tile (A: m, B: n)
    const int hf = lane >> 5;      // k-half (16B) within a 32B k-slice
    const int rx = rA & 7;         // swizzle key

    for (int k0 = 0; k0 < K; k0 += BKQ) {
        __syncthreads();   // previous iteration's LDS reads done
#pragma unroll
        for (int u = 0; u < 4; u++) {
            load_lds16(ag + u * band, lA + u * 4096);
            load_lds16(bg + u * band, lB + u * 4096);
        }
        ag += BKQ;
        bg += BKQ;
        __syncthreads();   // staging drained (implicit vmcnt(0))

#pragma unroll
        for (int ss = 0; ss < 4; ss++) {
            const int pc = (((ss * 2 + hf) ^ rx) << 4);  // phys byte offset
            int32x4 a0 = *(const int32x4*)(As + (wm + rA) * 128 + pc);
            int32x4 a1 = *(const int32x4*)(As + (wm + 32 + rA) * 128 + pc);
            int32x4 b0 = *(const int32x4*)(Bs + (wn + rA) * 128 + pc);
            int32x4 b1 = *(const int32x4*)(Bs + (wn + 32 + rA) * 128 + pc);
            acc[0][0] = __builtin_amdgcn_mfma_i32_32x32x32_i8(a0, b0, acc[0][0], 0, 0, 0);
            acc[0][1] = __builtin_amdgcn_mfma_i32_32x32x32_i8(a0, b1, acc[0][1], 0, 0, 0);
            acc[1][0] = __builtin_amdgcn_mfma_i32_32x32x32_i8(a1, b0, acc[1][0], 0, 0, 0);
            acc[1][1] = __builtin_amdgcn_mfma_i32_32x32x32_i8(a1, b1, acc[1][1], 0, 0, 0);
        }
    }

    // epilogue: C/D col=lane&31, row=(reg&3)+8*(reg>>2)+4*(lane>>5).
    // mkscales fused: alpha = a_s*w_s[n], beta = alpha*(128 - w_zp[n]).
    const float as = ascale[0];
#pragma unroll
    for (int nt = 0; nt < 2; nt++) {
        const int col = n0 + wn + nt * 32 + rA;
        const float al = as * wscale[col];
        const float be = al * (float)(128 - wzp[col]);
        const float bi = bias[col];
#pragma unroll
        for (int mt = 0; mt < 2; mt++) {
#pragma unroll
            for (int t = 0; t < 16; t++) {
                const int row = m0 + wm + mt * 32 + (t & 3) + 8 * (t >> 2) + 4 * hf;
                C[(size_t)row * N + col] =
                    al * (float)acc[mt][nt][t] + be * (float)rowsum[row] + bi;
            }
        }
    }
}

// ---------------------------------------------------------------------------
extern "C" void kernel_launch(void* const* d_in, const int* in_sizes, int n_in,
                              void* d_out, int out_size, void* d_ws, size_t ws_size,
                              hipStream_t stream) {
    const float* x      = (const float*)d_in[0];
    const int*   wq     = (const int*)d_in[1];
    const float* wscale = (const float*)d_in[2];
    const int*   wzp    = (const int*)d_in[3];
    const float* ascale = (const float*)d_in[4];
    const int*   azp    = (const int*)d_in[5];
    const float* bias   = (const float*)d_in[6];
    float* out = (float*)d_out;

    const int N = in_sizes[2];          // OUT
    const int K = in_sizes[1] / N;      // IN
    const int M = in_sizes[0] / K;      // B*S

    char* ws     = (char*)d_ws;
    char* xs     = ws;                                 // M*K int8
    char* wsq    = ws + (size_t)M * K;                 // N*K int8
    int*  rowsum = (int*)(wsq + (size_t)N * K);        // M int32

    long n4 = (long)N * K / 4;
    int wblocks = (int)((n4 + 255) / 256);
    prep<<<M + wblocks, 256, 0, stream>>>(
        x, ascale, azp, xs, rowsum, K, M, (const int4*)wq, (char4*)wsq, n4);

    dim3 grid(N / BN, M / BM);
    gemm_i8<<<grid, 256, 0, stream>>>(
        xs, wsq, rowsum, wscale, wzp, ascale, bias, out, M, N, K);
}